// Round 4
// baseline (47.367 us; speedup 1.0000x reference)
//
#include <hip/hip_runtime.h>
#include <hip/hip_bf16.h>

typedef _Float16 half8 __attribute__((ext_vector_type(8)));
typedef float f32x4 __attribute__((ext_vector_type(4)));

#define N_U      4096
#define N_L      65536
#define NZ       32
#define NSPLIT   256                  // L splits (grid.x of kA)
#define LSLICE   (N_L / NSPLIT)       // 256 L rows per block
#define UT       4                    // u-tiles per wave (16 rows each)
#define BM       256                  // U rows per kA block (4 waves x 4 tiles x 16)
#define GY       (N_U / BM)           // 16
#define XCHUNK   16                   // x-values reduced per kB1 block

// workspace layout
#define OFF_MM   0                    // 2 x u32: [0]=max(dd) bits, [1]=min(dd) bits
#define OFF_P    1024                 // float P[NSPLIT][N_U]  (4 MB)
#define OFF_LF   (OFF_P  + NSPLIT * N_U * 4)        // _Float16 Lf16[N_L][32] (4 MB)
#define OFF_LSQ  (OFF_LF + N_L * NZ * 2)            // float lsqh[N_L] = -0.5*||l||^2
#define OFF_UF   (OFF_LSQ + N_L * 4)                // _Float16 Uf16[N_U][32]
#define OFF_P2   (OFF_UF + N_U * NZ * 2)            // float P2[16][N_U] (256 KB)

// ---------------------------------------------------------------------------
// Precompute: L -> f16 rows + (-0.5*||l||^2), U -> f16 rows; init min/max slots
__global__ __launch_bounds__(256) void kPre(const float* __restrict__ Uz,
                                            const float* __restrict__ Lz,
                                            _Float16* __restrict__ Lf16,
                                            float* __restrict__ lsqh,
                                            _Float16* __restrict__ Uf16,
                                            unsigned int* __restrict__ mm) {
    int r = blockIdx.x * 256 + threadIdx.x;
    if (r == 0) { mm[0] = 0u; mm[1] = 0xFFFFFFFFu; }
    if (r < N_L) {
        const f32x4* src = (const f32x4*)(Lz + (size_t)r * NZ);
        _Float16* dst = Lf16 + (size_t)r * NZ;
        float s = 0.f;
#pragma unroll
        for (int j = 0; j < 4; ++j) {
            f32x4 a = src[2 * j], b = src[2 * j + 1];
            s = fmaf(a[0], a[0], s); s = fmaf(a[1], a[1], s);
            s = fmaf(a[2], a[2], s); s = fmaf(a[3], a[3], s);
            s = fmaf(b[0], b[0], s); s = fmaf(b[1], b[1], s);
            s = fmaf(b[2], b[2], s); s = fmaf(b[3], b[3], s);
            *(half8*)(dst + j * 8) =
                (half8){(_Float16)a[0], (_Float16)a[1], (_Float16)a[2], (_Float16)a[3],
                        (_Float16)b[0], (_Float16)b[1], (_Float16)b[2], (_Float16)b[3]};
        }
        lsqh[r] = -0.5f * s;
    } else if (r < N_L + N_U) {
        int u = r - N_L;
        const f32x4* src = (const f32x4*)(Uz + (size_t)u * NZ);
        _Float16* dst = Uf16 + (size_t)u * NZ;
#pragma unroll
        for (int j = 0; j < 4; ++j) {
            f32x4 a = src[2 * j], b = src[2 * j + 1];
            *(half8*)(dst + j * 8) =
                (half8){(_Float16)a[0], (_Float16)a[1], (_Float16)a[2], (_Float16)a[3],
                        (_Float16)b[0], (_Float16)b[1], (_Float16)b[2], (_Float16)b[3]};
        }
    }
}

// ---------------------------------------------------------------------------
// Heavy kernel: P[x][u] = max over L-slice x of (u.l - 0.5*||l||^2).
// 8-waves/SIMD occupancy target (VGPR<=64), manual 1-iter prefetch,
// batched MFMA->acc[] then fused max reduce (no mfma->valu stall pairs).
__global__ __launch_bounds__(256, 8) void kA(const _Float16* __restrict__ Lf16,
                                             const float* __restrict__ lsqh,
                                             const _Float16* __restrict__ Uf16,
                                             float* __restrict__ P) {
    const int tid  = threadIdx.x;
    const int lane = tid & 63;
    const int wave = tid >> 6;
    const int g    = lane >> 4;    // k-chunk 0..3 (k = g*8 + e, same perm for A and B)
    const int lc   = lane & 15;

    const int ubase = blockIdx.y * BM + wave * (UT * 16);
    const int lbase = blockIdx.x * LSLICE;

    half8 bfrag[UT];
#pragma unroll
    for (int t = 0; t < UT; ++t)
        bfrag[t] = *(const half8*)(Uf16 + (size_t)(ubase + t * 16 + lc) * NZ + g * 8);

    float maxv[UT];
#pragma unroll
    for (int t = 0; t < UT; ++t) maxv[t] = -INFINITY;

    const _Float16* aptr = Lf16 + (size_t)(lbase + lc) * NZ + g * 8;
    const float*    cptr = lsqh + lbase + g * 4;

    half8 afrag = *(const half8*)aptr;
    f32x4 cc    = *(const f32x4*)cptr;

    for (int lt = 0; lt < LSLICE / 16; ++lt) {
        const int nlt = (lt + 1) & (LSLICE / 16 - 1);     // wrap: always in-bounds
        half8 anext = *(const half8*)(aptr + (size_t)nlt * 16 * NZ);
        f32x4 cnext = *(const f32x4*)(cptr + nlt * 16);

        f32x4 acc[UT];
#pragma unroll
        for (int t = 0; t < UT; ++t)
            acc[t] = __builtin_amdgcn_mfma_f32_16x16x32_f16(afrag, bfrag[t], cc, 0, 0, 0);
#pragma unroll
        for (int t = 0; t < UT; ++t)
            maxv[t] = fmaxf(fmaxf(fmaxf(acc[t][0], acc[t][1]),
                                  fmaxf(acc[t][2], acc[t][3])), maxv[t]);
        afrag = anext;
        cc    = cnext;
    }

#pragma unroll
    for (int t = 0; t < UT; ++t) {
        float v = maxv[t];
        v = fmaxf(v, __shfl_xor(v, 16));
        v = fmaxf(v, __shfl_xor(v, 32));
        if (g == 0)
            P[(size_t)blockIdx.x * N_U + ubase + t * 16 + lc] = v;  // coalesced store
    }
}

// ---------------------------------------------------------------------------
// Stage 1 reduce: P[256][N_U] -> P2[16][N_U].  grid (16 x-chunks, 16 u-chunks)
__global__ __launch_bounds__(256) void kB1(const float* __restrict__ P,
                                           float* __restrict__ P2) {
    const int xc = blockIdx.x;                 // 0..15
    const int u  = blockIdx.y * 256 + threadIdx.x;
    float m = -INFINITY;
#pragma unroll
    for (int k = 0; k < XCHUNK; ++k)
        m = fmaxf(m, P[(size_t)(xc * XCHUNK + k) * N_U + u]);
    P2[(size_t)xc * N_U + u] = m;
}

// ---------------------------------------------------------------------------
// Stage 2: finish reduce, compute dd, global min/max via wave reduce + atomics
__global__ __launch_bounds__(256) void kB2(const float* __restrict__ Uz,
                                           const float* __restrict__ P2,
                                           float* __restrict__ out,
                                           unsigned int* __restrict__ mm) {
    int u = blockIdx.x * 256 + threadIdx.x;
    float m = -INFINITY;
#pragma unroll
    for (int x = 0; x < 16; ++x) m = fmaxf(m, P2[(size_t)x * N_U + u]);

    const f32x4* p = (const f32x4*)(Uz + (size_t)u * NZ);
    float s = 0.f;
#pragma unroll
    for (int j = 0; j < 8; ++j) {
        f32x4 v = p[j];
        s = fmaf(v[0], v[0], s); s = fmaf(v[1], v[1], s);
        s = fmaf(v[2], v[2], s); s = fmaf(v[3], v[3], s);
    }
    float sq  = fmaxf(fmaf(-2.f, m, s), 0.f);      // ||u||^2 + min(||l||^2 - 2 u.l)
    float div = sqrtf(sq);
    float dens = -0.5f * s - 29.406033062549525f;  // -0.5*||u||^2 - 16*log(2pi)
    float dd = expf(dens) * (div + 1e-18f);
    out[u] = dd;

    unsigned int b = __float_as_uint(dd);          // dd >= 0 -> uint order == float order
    unsigned int bmx = b, bmn = b;
#pragma unroll
    for (int o = 1; o < 64; o <<= 1) {
        bmx = max(bmx, (unsigned int)__shfl_xor((int)bmx, o));
        bmn = min(bmn, (unsigned int)__shfl_xor((int)bmn, o));
    }
    if ((threadIdx.x & 63) == 0) {
        atomicMax(&mm[0], bmx);
        atomicMin(&mm[1], bmn);
    }
}

// ---------------------------------------------------------------------------
__global__ __launch_bounds__(256) void kC(float* __restrict__ out,
                                          const unsigned int* __restrict__ mm) {
    int u = blockIdx.x * 256 + threadIdx.x;
    float mx = __uint_as_float(mm[0]);
    float mn = __uint_as_float(mm[1]);
    out[u] = (out[u] - mn) / ((mx - mn) + 1e-18f);
}

// ---------------------------------------------------------------------------
extern "C" void kernel_launch(void* const* d_in, const int* in_sizes, int n_in,
                              void* d_out, int out_size, void* d_ws, size_t ws_size,
                              hipStream_t stream) {
    const float* Uz = (const float*)d_in[1];
    const float* Lz = (const float*)d_in[2];
    float* out = (float*)d_out;
    unsigned char* ws = (unsigned char*)d_ws;

    unsigned int* mm   = (unsigned int*)(ws + OFF_MM);
    float*        Pp   = (float*)(ws + OFF_P);
    _Float16*     Lf16 = (_Float16*)(ws + OFF_LF);
    float*        lsqh = (float*)(ws + OFF_LSQ);
    _Float16*     Uf16 = (_Float16*)(ws + OFF_UF);
    float*        P2   = (float*)(ws + OFF_P2);

    kPre<<<(N_L + N_U + 255) / 256, 256, 0, stream>>>(Uz, Lz, Lf16, lsqh, Uf16, mm);
    dim3 grid(NSPLIT, GY);   // 256 x 16 = 4096 blocks
    kA<<<grid, 256, 0, stream>>>(Lf16, lsqh, Uf16, Pp);
    dim3 gB1(16, 16);
    kB1<<<gB1, 256, 0, stream>>>(Pp, P2);
    kB2<<<N_U / 256, 256, 0, stream>>>(Uz, P2, out, mm);
    kC<<<N_U / 256, 256, 0, stream>>>(out, mm);
}

// Round 5
// 44.231 us; speedup vs baseline: 1.0709x; 1.0709x over previous
//
#include <hip/hip_runtime.h>
#include <hip/hip_bf16.h>

typedef _Float16 half8 __attribute__((ext_vector_type(8)));
typedef float f32x4 __attribute__((ext_vector_type(4)));
typedef unsigned int u32x4 __attribute__((ext_vector_type(4)));

#define N_U      4096
#define N_L      65536
#define NZ       32
#define NSPLIT   256                  // L splits (grid.x of kA)
#define LSLICE   (N_L / NSPLIT)       // 256 L rows per block
#define UT       8                    // u-tiles per wave
#define BM       512                  // U rows per kA block (4 waves x 8 x 16)
#define GY       (N_U / BM)           // 8

// workspace layout
#define OFF_P1   0                            // u32 P1key[N_U] (16 KB)
#define OFF_USQ  (16 * 1024)                  // float usq[N_U]  (16 KB)
#define OFF_LF   (32 * 1024)                  // _Float16 Lf16[N_L][32] (4 MB)
#define OFF_LSQ  (OFF_LF + N_L * NZ * 2)      // float lsqh[N_L] = -0.5*||l||^2
#define OFF_UF   (OFF_LSQ + N_L * 4)          // _Float16 Uf16[N_U][32]

// Order-preserving float <-> uint key (monotone for all finite floats)
__device__ __forceinline__ unsigned int f2key(float f) {
    unsigned int u = __float_as_uint(f);
    return (u & 0x80000000u) ? ~u : (u | 0x80000000u);
}
__device__ __forceinline__ float key2f(unsigned int k) {
    unsigned int u = (k & 0x80000000u) ? (k & 0x7FFFFFFFu) : ~k;
    return __uint_as_float(u);
}

// ---------------------------------------------------------------------------
// Precompute: L -> f16 + (-0.5*||l||^2); U -> f16 + ||u||^2; init P1key.
__global__ __launch_bounds__(256) void kPre(const float* __restrict__ Uz,
                                            const float* __restrict__ Lz,
                                            _Float16* __restrict__ Lf16,
                                            float* __restrict__ lsqh,
                                            _Float16* __restrict__ Uf16,
                                            float* __restrict__ usq,
                                            unsigned int* __restrict__ P1key) {
    int r = blockIdx.x * 256 + threadIdx.x;
    if (r < N_L) {
        const f32x4* src = (const f32x4*)(Lz + (size_t)r * NZ);
        _Float16* dst = Lf16 + (size_t)r * NZ;
        float s = 0.f;
#pragma unroll
        for (int j = 0; j < 4; ++j) {
            f32x4 a = src[2 * j], b = src[2 * j + 1];
            s = fmaf(a[0], a[0], s); s = fmaf(a[1], a[1], s);
            s = fmaf(a[2], a[2], s); s = fmaf(a[3], a[3], s);
            s = fmaf(b[0], b[0], s); s = fmaf(b[1], b[1], s);
            s = fmaf(b[2], b[2], s); s = fmaf(b[3], b[3], s);
            *(half8*)(dst + j * 8) =
                (half8){(_Float16)a[0], (_Float16)a[1], (_Float16)a[2], (_Float16)a[3],
                        (_Float16)b[0], (_Float16)b[1], (_Float16)b[2], (_Float16)b[3]};
        }
        lsqh[r] = -0.5f * s;
    } else if (r < N_L + N_U) {
        int u = r - N_L;
        const f32x4* src = (const f32x4*)(Uz + (size_t)u * NZ);
        _Float16* dst = Uf16 + (size_t)u * NZ;
        float s = 0.f;
#pragma unroll
        for (int j = 0; j < 4; ++j) {
            f32x4 a = src[2 * j], b = src[2 * j + 1];
            s = fmaf(a[0], a[0], s); s = fmaf(a[1], a[1], s);
            s = fmaf(a[2], a[2], s); s = fmaf(a[3], a[3], s);
            s = fmaf(b[0], b[0], s); s = fmaf(b[1], b[1], s);
            s = fmaf(b[2], b[2], s); s = fmaf(b[3], b[3], s);
            *(half8*)(dst + j * 8) =
                (half8){(_Float16)a[0], (_Float16)a[1], (_Float16)a[2], (_Float16)a[3],
                        (_Float16)b[0], (_Float16)b[1], (_Float16)b[2], (_Float16)b[3]};
        }
        usq[u] = s;
        P1key[u] = 0u;   // key-space -inf
    }
}

// ---------------------------------------------------------------------------
// Heavy kernel: atomicMax over L-slices of key(u.l - 0.5*||l||^2).
// Minimal inner loop: 2 loads + 2 ptr bumps + 8 MFMA + ~16-24 max ops.
__global__ __launch_bounds__(256) void kA(const _Float16* __restrict__ Lf16,
                                          const float* __restrict__ lsqh,
                                          const _Float16* __restrict__ Uf16,
                                          unsigned int* __restrict__ P1key) {
    const int tid  = threadIdx.x;
    const int lane = tid & 63;
    const int wave = tid >> 6;
    const int g    = lane >> 4;    // k-chunk 0..3 (k = g*8+e, same perm A and B)
    const int lc   = lane & 15;

    const int ubase = blockIdx.y * BM + wave * (UT * 16);
    const int lbase = blockIdx.x * LSLICE;

    half8 bfrag[UT];
#pragma unroll
    for (int t = 0; t < UT; ++t)
        bfrag[t] = *(const half8*)(Uf16 + (size_t)(ubase + t * 16 + lc) * NZ + g * 8);

    float maxv[UT];
#pragma unroll
    for (int t = 0; t < UT; ++t) maxv[t] = -INFINITY;

    const half8* aptr = (const half8*)(Lf16 + (size_t)(lbase + lc) * NZ + g * 8);
    const f32x4* cptr = (const f32x4*)(lsqh + lbase + g * 4);

#pragma unroll 2
    for (int lt = 0; lt < LSLICE / 16; ++lt) {
        half8 afrag = *aptr; aptr += (16 * NZ) / 8;   // +16 rows
        f32x4 cc    = *cptr; cptr += 4;               // +16 floats
#pragma unroll
        for (int t = 0; t < UT; ++t) {
            f32x4 a = __builtin_amdgcn_mfma_f32_16x16x32_f16(afrag, bfrag[t], cc, 0, 0, 0);
            // max3-fusable: max3(a0,a1,a2) then max3(that, a3, maxv)
            maxv[t] = fmaxf(fmaxf(fmaxf(a[0], a[1]), a[2]), fmaxf(a[3], maxv[t]));
        }
    }

#pragma unroll
    for (int t = 0; t < UT; ++t) {
        float v = maxv[t];
        v = fmaxf(v, __shfl_xor(v, 16));
        v = fmaxf(v, __shfl_xor(v, 32));
        if (g == 0)
            atomicMax(&P1key[ubase + t * 16 + lc], f2key(v));
    }
}

// ---------------------------------------------------------------------------
// Single-block finisher: dd, global min/max, normalize. Reads 32 KB only.
__global__ __launch_bounds__(1024) void kB(const unsigned int* __restrict__ P1key,
                                           const float* __restrict__ usq,
                                           float* __restrict__ out) {
    const int t    = threadIdx.x;       // 0..1023, each handles 4 u's
    const int lane = t & 63;
    const int wid  = t >> 6;

    u32x4 kv = ((const u32x4*)P1key)[t];
    f32x4 uq = ((const f32x4*)usq)[t];

    float dd[4], lmin = INFINITY, lmax = -INFINITY;
#pragma unroll
    for (int j = 0; j < 4; ++j) {
        float M   = key2f(kv[j]);                       // max(u.l - 0.5||l||^2)
        float sq  = fmaxf(fmaf(-2.f, M, uq[j]), 0.f);   // min squared distance
        float dens = -0.5f * uq[j] - 29.406033062549525f;
        dd[j] = expf(dens) * (sqrtf(sq) + 1e-18f);
        lmin = fminf(lmin, dd[j]);
        lmax = fmaxf(lmax, dd[j]);
    }

    __shared__ float smn[16], smx[16];
#pragma unroll
    for (int o = 1; o < 64; o <<= 1) {
        lmin = fminf(lmin, __shfl_xor(lmin, o));
        lmax = fmaxf(lmax, __shfl_xor(lmax, o));
    }
    if (lane == 0) { smn[wid] = lmin; smx[wid] = lmax; }
    __syncthreads();
    if (wid == 0) {
        float a = (lane < 16) ? smn[lane] : INFINITY;
        float b = (lane < 16) ? smx[lane] : -INFINITY;
#pragma unroll
        for (int o = 1; o < 16; o <<= 1) {
            a = fminf(a, __shfl_xor(a, o));
            b = fmaxf(b, __shfl_xor(b, o));
        }
        if (lane == 0) { smn[0] = a; smx[0] = b; }
    }
    __syncthreads();
    float mn = smn[0], mx = smx[0];
    float inv = 1.f / ((mx - mn) + 1e-18f);

    f32x4 o4 = (f32x4){(dd[0] - mn) * inv, (dd[1] - mn) * inv,
                       (dd[2] - mn) * inv, (dd[3] - mn) * inv};
    ((f32x4*)out)[t] = o4;
}

// ---------------------------------------------------------------------------
extern "C" void kernel_launch(void* const* d_in, const int* in_sizes, int n_in,
                              void* d_out, int out_size, void* d_ws, size_t ws_size,
                              hipStream_t stream) {
    const float* Uz = (const float*)d_in[1];
    const float* Lz = (const float*)d_in[2];
    float* out = (float*)d_out;
    unsigned char* ws = (unsigned char*)d_ws;

    unsigned int* P1key = (unsigned int*)(ws + OFF_P1);
    float*        usq   = (float*)(ws + OFF_USQ);
    _Float16*     Lf16  = (_Float16*)(ws + OFF_LF);
    float*        lsqh  = (float*)(ws + OFF_LSQ);
    _Float16*     Uf16  = (_Float16*)(ws + OFF_UF);

    kPre<<<(N_L + N_U + 255) / 256, 256, 0, stream>>>(Uz, Lz, Lf16, lsqh, Uf16, usq, P1key);
    dim3 grid(NSPLIT, GY);   // 256 x 8 = 2048 blocks
    kA<<<grid, 256, 0, stream>>>(Lf16, lsqh, Uf16, P1key);
    kB<<<1, 1024, 0, stream>>>(P1key, usq, out);
}